// Round 11
// baseline (303.337 us; speedup 1.0000x reference)
//
#include <hip/hip_runtime.h>
#include <math.h>

// q,k,v: [B=2, H=16, N=2048, Dh=64] fp32.  BH = 32 independent heads.
#define BH 32
#define NN 2048
#define DD 64
#define BHNN (BH * NN)        // 65536 rows total
#define QK ((size_t)BH * NN * DD)  // 4,194,304 elems per tensor

// 8 * log2(e): logits produced in base-2 domain so all softmax exps are a bare
// v_exp_f32 (exp2). Softmax is invariant to the base change.
#define QSCALE 11.5415603f

// R21: T15-style two-accumulator software pipeline (single-tile granularity)
// in both heavy kernels. Measured R10 state: MfmaUtil 13.3%, VALUBusy ~50%,
// ~35-40% issue-idle at the register-capped 4 waves/SIMD -- per-wave serial
// (MFMA chain -> softmax) bubbles that cross-wave overlap can't fill.
// Pipeline: MFMA(t)->accA ; softmax(accB=t-1) ; MFMA(t+1)->accB ; softmax(accA).
// Static accA/accB naming + explicit peel/epilogue (rule #20: no runtime acc
// index). Single-tile softmax costs 2 exp2/logit vs paired 1.5 -- cheap vs
// the ~500cyc/mti serialization it removes.
//
// Register ledger (unified VGPR+AGPR, cap 128 at 4 waves/SIMD; spill wall
// measured at every structure with >=64 acc regs: R12/R15):
//   stats: accA/B 32 + ah 16 + m/d 32 + temps ~20 ~= 100 <= 128.
//   wsum:  accA/B 32 + ah 16 + mb 16 + wacc 4 + temps ~20 ~= 108 <= 128.
//
// R16 precision scheme (kept): SINGLE fp16 q x fp16 k MFMA per k-slice.
// K layout (R14, kept): khi = 16KB tiles [bh][tile][128 rows][64 cols],
// intra-row swizzle: granule j at j ^ (row&7); global_load_lds stages
// LINEARLY; ds_read applies the same XOR.
typedef __attribute__((ext_vector_type(8)))  _Float16 halfx8;
typedef __attribute__((ext_vector_type(4)))  _Float16 halfx4;
typedef __attribute__((ext_vector_type(16))) float    floatx16;

__device__ inline float fexp2(float x) { return __builtin_amdgcn_exp2f(x); }
__device__ inline float flog2(float x) { return __builtin_amdgcn_logf(x); }

// C/D row for accumulator register r (0..15) given half = lane>>5 (verified R2).
__device__ inline int rowmap(int r, int half) {
    return (r & 3) + 8 * (r >> 2) + 4 * half;
}

// ---------------------------------------------------------------------------
// Pre-convert: q -> fp16 (QSCALE folded), k -> fp16, k swizzled.
// ---------------------------------------------------------------------------
__global__ __launch_bounds__(256) void convert_kernel(const float4* __restrict__ q,
                                                      const float4* __restrict__ k,
                                                      _Float16* __restrict__ qhi,
                                                      _Float16* __restrict__ khi) {
    size_t gid = (size_t)blockIdx.x * 256 + threadIdx.x;  // float4 index, QK/4 total
    float4 qa = q[gid];
    float4 ka = k[gid];
    float qf[4] = {qa.x, qa.y, qa.z, qa.w};
    float kf[4] = {ka.x, ka.y, ka.z, ka.w};
    halfx4 h, kh;
#pragma unroll
    for (int i = 0; i < 4; ++i) {
        h[i]  = (_Float16)(qf[i] * QSCALE);  // RN
        kh[i] = (_Float16)kf[i];
    }
    *(halfx4*)&qhi[gid * 4] = h;
    // swizzled K: row = (gid>>4)&127; granule j = (gid>>1)&7; sub = (gid&1)*4
    size_t rowbase = (gid * 4) & ~(size_t)63;
    int j = (int)((gid >> 1) & 7) ^ (int)((gid >> 4) & 7);
    *(halfx4*)&khi[rowbase + (size_t)(j << 3) + ((gid & 1) << 2)] = kh;
}

// ---------------------------------------------------------------------------
// Async stage: one 16KB K-tile image -> LDS, linear copy, no VGPR round-trip.
// LDS dest = wave-uniform base + lane*16 (HW rule); global src per-lane.
// Tracked by vmcnt; __syncthreads() drains it.  4-wave and 8-wave variants.
// ---------------------------------------------------------------------------
__device__ inline void stage_tile_async4(const _Float16* __restrict__ gtile,
                                         _Float16* lds, int wave, int lane) {
#pragma unroll
    for (int i = 0; i < 4; ++i) {
        const char* gp = (const char*)gtile + wave * 4096 + i * 1024 + lane * 16;
        char* lp = (char*)lds + wave * 4096 + i * 1024;   // wave-uniform
        __builtin_amdgcn_global_load_lds(
            (const __attribute__((address_space(1))) unsigned int*)gp,
            (__attribute__((address_space(3))) unsigned int*)lp, 16, 0, 0);
    }
}
__device__ inline void stage_tile_async8(const _Float16* __restrict__ gtile,
                                         _Float16* lds, int wave, int lane) {
#pragma unroll
    for (int i = 0; i < 2; ++i) {
        const char* gp = (const char*)gtile + wave * 2048 + i * 1024 + lane * 16;
        char* lp = (char*)lds + wave * 2048 + i * 1024;   // wave-uniform
        __builtin_amdgcn_global_load_lds(
            (const __attribute__((address_space(1))) unsigned int*)gp,
            (__attribute__((address_space(3))) unsigned int*)lp, 16, 0, 0);
    }
}

// ---- A-operand fragments: lane holds A[m=lane&31][k=(lane>>5)*8+j] ----------
__device__ inline void load_a(const _Float16* __restrict__ qhi_row,
                              int half, halfx8 ah[4]) {
#pragma unroll
    for (int ks = 0; ks < 4; ++ks)
        ah[ks] = *(const halfx8*)&qhi_row[ks * 16 + half * 8];
}

// ---- one 32x32 logit tile: 4 chained MFMAs; caller pre-inits acc ------------
__device__ inline void mfma_tile(const _Float16* __restrict__ Kc, int t,
                                 int l31, int half, int xr,
                                 const halfx8 ah[4], floatx16& acc) {
    const int mr = t * 32 + l31;
    const _Float16* rowp = Kc + (size_t)mr * 64;
#pragma unroll
    for (int ks = 0; ks < 4; ++ks) {
        const int j = (ks * 2 + half) ^ xr;
        halfx8 bhf = *(const halfx8*)&rowp[j << 3];
        acc = __builtin_amdgcn_mfma_f32_32x32x16_f16(ah[ks], bhf, acc, 0, 0, 0);
    }
}

// ---- single-tile online softmax update (base-2), register-only --------------
__device__ inline void sm_update(const floatx16& acc, float m_run[16], float d_run[16]) {
#pragma unroll
    for (int r = 0; r < 16; ++r) {
        float m_new = fmaxf(m_run[r], acc[r]);
        float s  = fexp2(acc[r] - m_new);
        float rs = fexp2(m_run[r] - m_new);
        d_run[r] = fmaf(d_run[r], rs, s);
        m_run[r] = m_new;
    }
}

// ---- sum of exp2 over a tile's 16 accumulator rows (2 partials for ILP) -----
__device__ inline float red_exp(const floatx16& acc) {
    float s0 = 0.f, s1 = 0.f;
#pragma unroll
    for (int r = 0; r < 16; r += 2) {
        s0 += fexp2(acc[r]);
        s1 += fexp2(acc[r + 1]);
    }
    return s0 + s1;
}

#define ZACC(a) { _Pragma("unroll") for (int e_ = 0; e_ < 16; ++e_) (a)[e_] = 0.f; }

// ---------------------------------------------------------------------------
// Phase 1 (R21 pipelined): per-row softmax stats (base-2), PARTIAL over an
// m-half.  R6 launch shape (grid 1024 x 256thr, (256,4), async4 dbuf staging).
// Inner loop: two-acc software pipeline, softmax always overlapping an
// in-flight MFMA chain.  Peeled first tile; epilogue softmax after the loop.
// ---------------------------------------------------------------------------
__global__ __launch_bounds__(256, 4) void stats_kernel(const _Float16* __restrict__ qhi,
                                                       const _Float16* __restrict__ khi,
                                                       float* __restrict__ smax_p,
                                                       float* __restrict__ sden_p) {
    __shared__ _Float16 K2[2 * 128 * 64];  // 32 KB, two tile buffers
    const int g    = blockIdx.x & 63;      // bh + 32*ms
    const int bh   = g & 31;
    const int ms   = g >> 5;               // m-split: tiles [ms*8, ms*8+8)
    const int n0   = (blockIdx.x >> 6) * 128;
    const int tid  = threadIdx.x;
    const int wave = tid >> 6, lane = tid & 63;
    const int half = lane >> 5, l31 = lane & 31;
    const int xr   = l31 & 7;              // row&7 for swizzled reads
    const size_t base = (size_t)bh * NN * DD;

    const _Float16* khi_b = khi + base;
    stage_tile_async4(khi_b + (size_t)(ms * 8) * 8192, K2, wave, lane);

    // A fragments: fixed rows for the whole kernel.
    halfx8 ah[4];
    {
        size_t ro = base + (size_t)(n0 + wave * 32 + l31) * DD;
        load_a(qhi + ro, half, ah);
    }

    float m_run[16], d_run[16];
#pragma unroll
    for (int r = 0; r < 16; ++r) { m_run[r] = -INFINITY; d_run[r] = 0.f; }

    floatx16 accA, accB;
    __syncthreads();                       // tile 0 landed (vmcnt drain) + barrier

    {   // ---- mti = 0, peeled (no pending accB on entry) ----
        const _Float16* Kc = K2;
        stage_tile_async4(khi_b + (size_t)(ms * 8 + 1) * 8192, K2 + 8192, wave, lane);
        ZACC(accA); mfma_tile(Kc, 0, l31, half, xr, ah, accA);
        ZACC(accB); mfma_tile(Kc, 1, l31, half, xr, ah, accB);
        sm_update(accA, m_run, d_run);
        ZACC(accA); mfma_tile(Kc, 2, l31, half, xr, ah, accA);
        sm_update(accB, m_run, d_run);
        ZACC(accB); mfma_tile(Kc, 3, l31, half, xr, ah, accB);
        sm_update(accA, m_run, d_run);
        __syncthreads();                   // tile 1 landed; all reads of buf0 done
    }

#pragma unroll 1
    for (int mti = 1; mti < 8; ++mti) {    // steady state: accB = prev t3 pending
        const _Float16* Kc = K2 + (mti & 1) * 8192;
        if (mti < 7)
            stage_tile_async4(khi_b + (size_t)(ms * 8 + mti + 1) * 8192,
                              K2 + ((mti + 1) & 1) * 8192, wave, lane);
        ZACC(accA); mfma_tile(Kc, 0, l31, half, xr, ah, accA);
        sm_update(accB, m_run, d_run);     // prev tile 3, overlaps tile-0 chain
        ZACC(accB); mfma_tile(Kc, 1, l31, half, xr, ah, accB);
        sm_update(accA, m_run, d_run);
        ZACC(accA); mfma_tile(Kc, 2, l31, half, xr, ah, accA);
        sm_update(accB, m_run, d_run);
        ZACC(accB); mfma_tile(Kc, 3, l31, half, xr, ah, accB);
        sm_update(accA, m_run, d_run);
        if (mti < 7) __syncthreads();
    }
    sm_update(accB, m_run, d_run);         // final tile 3

    // Cross-lane combine within each 32-lane half (rows differ across halves).
    float* smp = smax_p + ((size_t)ms * BH + bh) * NN;
    float* sdp = sden_p + ((size_t)ms * BH + bh) * NN;
#pragma unroll
    for (int r = 0; r < 16; ++r) {
        float M = m_run[r];
#pragma unroll
        for (int off = 1; off < 32; off <<= 1)
            M = fmaxf(M, __shfl_xor(M, off));
        float dd = d_run[r] * fexp2(m_run[r] - M);
#pragma unroll
        for (int off = 1; off < 32; off <<= 1)
            dd += __shfl_xor(dd, off);
        if (l31 == 0) {
            int row = n0 + wave * 32 + rowmap(r, half);
            smp[row] = M;
            sdp[row] = dd;
        }
    }
}

// ---------------------------------------------------------------------------
// Phase 2 (R21 pipelined): w[m] over ALL rows + fused output.  Grid 512 =
// bh + 32*m0i, 512 threads (8 waves).  Ms holds -(M + log2 den); per strip
// the 16 row-constants are cached in regs (mb) and used as the MFMA C-init,
// so the reduce is a bare sum of exp2.  Two-acc pipeline: reduce(prev tile)
// overlaps the next tile's MFMA chain; wacc targets statically unrolled.
// T14 v-prefetch kept.
// ---------------------------------------------------------------------------
__global__ __launch_bounds__(512, 4) void wsum_kernel(const _Float16* __restrict__ qhi,
                                                      const _Float16* __restrict__ khi,
                                                      const float* __restrict__ smax_p,
                                                      const float* __restrict__ sden_p,
                                                      const float* __restrict__ v,
                                                      float* __restrict__ out) {
    __shared__ _Float16 Khi[128 * 64];     // 16 KB, single tile
    __shared__ float Ms[2048];             // 8 KB: -(M + log2 den) for all rows
    __shared__ float wred[8 * 128];        // 4 KB
    __shared__ float wfin[128];
    const int b    = blockIdx.x;
    const int bh   = b & 31;
    const int m0   = (b >> 5) * 128;       // col block
    const int tid  = threadIdx.x;
    const int wave = tid >> 6, lane = tid & 63;
    const int half = lane >> 5, l31 = lane & 31;
    const int xr   = l31 & 7;
    const size_t base = (size_t)bh * NN * DD;

    stage_tile_async8(khi + base + (size_t)m0 * 64, Khi, wave, lane);

    {   // combine row stats inline (4 rows/thread) while the tile streams in
        size_t roff = (size_t)bh * NN + tid * 4;
        float4 m0v = *(const float4*)&smax_p[roff];
        float4 m1v = *(const float4*)&smax_p[(size_t)BHNN + roff];
        float4 d0v = *(const float4*)&sden_p[roff];
        float4 d1v = *(const float4*)&sden_p[(size_t)BHNN + roff];
        float mm0[4] = {m0v.x, m0v.y, m0v.z, m0v.w};
        float mm1[4] = {m1v.x, m1v.y, m1v.z, m1v.w};
        float dd0[4] = {d0v.x, d0v.y, d0v.z, d0v.w};
        float dd1[4] = {d1v.x, d1v.y, d1v.z, d1v.w};
#pragma unroll
        for (int j = 0; j < 4; ++j) {
            float M = fmaxf(mm0[j], mm1[j]);
            float den = dd0[j] * fexp2(mm0[j] - M) + dd1[j] * fexp2(mm1[j] - M);
            Ms[tid * 4 + j] = -(M + flog2(den));   // negated Madj
        }
    }
    __syncthreads();                       // K tile landed + Ms visible

    float wacc0 = 0.f, wacc1 = 0.f, wacc2 = 0.f, wacc3 = 0.f;
    floatx16 accA, accB;

#define MBINIT(a) { _Pragma("unroll") for (int e_ = 0; e_ < 16; ++e_) (a)[e_] = mb[e_]; }

    {   // ---- it = 0, peeled ----
        const int ls = wave;
        halfx8 ah[4];
        {
            size_t ro = base + (size_t)(ls * 32 + l31) * DD;
            load_a(qhi + ro, half, ah);
        }
        float mb[16];
#pragma unroll
        for (int e = 0; e < 16; ++e) mb[e] = Ms[ls * 32 + rowmap(e, half)];

        MBINIT(accA); mfma_tile(Khi, 0, l31, half, xr, ah, accA);
        MBINIT(accB); mfma_tile(Khi, 1, l31, half, xr, ah, accB);
        wacc0 += red_exp(accA);
        MBINIT(accA); mfma_tile(Khi, 2, l31, half, xr, ah, accA);
        wacc1 += red_exp(accB);
        MBINIT(accB); mfma_tile(Khi, 3, l31, half, xr, ah, accB);
        wacc2 += red_exp(accA);
    }

#pragma unroll 1
    for (int it = 1; it < 8; ++it) {       // steady: accB = prev tile 3 pending
        const int ls = wave + it * 8;
        halfx8 ah[4];
        {
            size_t ro = base + (size_t)(ls * 32 + l31) * DD;
            load_a(qhi + ro, half, ah);
        }
        float mb[16];
#pragma unroll
        for (int e = 0; e < 16; ++e) mb[e] = Ms[ls * 32 + rowmap(e, half)];

        MBINIT(accA); mfma_tile(Khi, 0, l31, half, xr, ah, accA);
        wacc3 += red_exp(accB);            // prev tile 3, overlaps tile-0 chain
        MBINIT(accB); mfma_tile(Khi, 1, l31, half, xr, ah, accB);
        wacc0 += red_exp(accA);
        MBINIT(accA); mfma_tile(Khi, 2, l31, half, xr, ah, accA);
        wacc1 += red_exp(accB);
        MBINIT(accB); mfma_tile(Khi, 3, l31, half, xr, ah, accB);
        wacc2 += red_exp(accA);
    }
    wacc3 += red_exp(accB);                // final tile 3

    // T14 v-prefetch: issue the epilogue's v reads now; they land under the
    // reduction barriers below.
    const float4* v4 = (const float4*)(v + base + (size_t)m0 * DD);
    float4 vpre[4];
#pragma unroll
    for (int i = 0; i < 4; ++i) vpre[i] = v4[tid + 512 * i];

    // halves hold same cols, different rows: fold halves, then the 8 waves.
    float wacc[4] = {wacc0, wacc1, wacc2, wacc3};
#pragma unroll
    for (int t = 0; t < 4; ++t) wacc[t] += __shfl_xor(wacc[t], 32);
    if (half == 0) {
#pragma unroll
        for (int t = 0; t < 4; ++t) wred[wave * 128 + t * 32 + l31] = wacc[t];
    }
    __syncthreads();
    if (tid < 128) {
        float s = 0.f;
#pragma unroll
        for (int w = 0; w < 8; ++w) s += wred[w * 128 + tid];
        wfin[tid] = s;
    }
    __syncthreads();

    // Fused epilogue: out[m, :] = wfin[m - m0] * v[m, :] for m in [m0, m0+128).
    float4* o4 = (float4*)(out + base + (size_t)m0 * DD);
#pragma unroll
    for (int i = 0; i < 4; ++i) {
        int idx = tid + 512 * i;           // 2048 float4s = 128 rows x 16
        float ww = wfin[idx >> 4];
        o4[idx] = make_float4(vpre[i].x * ww, vpre[i].y * ww,
                              vpre[i].z * ww, vpre[i].w * ww);
    }
}

extern "C" void kernel_launch(void* const* d_in, const int* in_sizes, int n_in,
                              void* d_out, int out_size, void* d_ws, size_t ws_size,
                              hipStream_t stream) {
    const float* q = (const float*)d_in[0];
    const float* k = (const float*)d_in[1];
    const float* v = (const float*)d_in[2];
    float* out = (float*)d_out;

    // Workspace (~17 MB), all fully rewritten each launch:
    _Float16* qhi = (_Float16*)d_ws;
    _Float16* khi = qhi + QK;
    float* smax_p = (float*)(khi + QK);       // 2*BHNN
    float* sden_p = smax_p + 2 * BHNN;        // 2*BHNN

    convert_kernel<<<QK / 4 / 256, 256, 0, stream>>>((const float4*)q, (const float4*)k,
                                                     qhi, khi);
    stats_kernel<<<1024, 256, 0, stream>>>(qhi, khi, smax_p, sden_p);
    wsum_kernel<<<512, 512, 0, stream>>>(qhi, khi, smax_p, sden_p, v, out);
}

// Round 13
// 156.255 us; speedup vs baseline: 1.9413x; 1.9413x over previous
//
#include <hip/hip_runtime.h>
#include <math.h>

// q,k,v: [B=2, H=16, N=2048, Dh=64] fp32.  BH = 32 independent heads.
#define BH 32
#define NN 2048
#define DD 64
#define BHNN (BH * NN)        // 65536 rows total
#define QK ((size_t)BH * NN * DD)  // 4,194,304 elems per tensor

// 8 * log2(e): logits produced in base-2 domain so all softmax exps are a bare
// v_exp_f32 (exp2). Softmax is invariant to the base change.
#define QSCALE 11.5415603f

// R23 = R22 resubmitted verbatim: the R12 bench died with a Trio-nursery
// infrastructure error (no pytest/compile/counter output) -- measurement
// lost, not failed. R22 = R20 (measured best, 155.5us) + T5 s_setprio
// around MFMA clusters.
//   R21 lesson (154us stats, 366MB scratch): interleaved two-acc pipeline
//   keeps accA+accB live across each other's softmax -> true demand >> 128
//   -> allocator scratches a whole accumulator. FIFTH confirmation of the
//   spill wall: any structure with >48 live accumulator-class regs spills.
//   T5 regime check: stats/wsum waves on a SIMD belong to INDEPENDENT
//   blocks (no cross-block barrier) -> naturally phase-staggered (m191
//   attn regime, not m190 lockstep GEMM) -> prioritizing MFMA-issuing
//   waves keeps the matrix pipe fed. SALU-only, zero reg cost.
//
// R20 content (all measured):
//   - stats: R6 shape (grid 1024 x 256thr, (256,4), async4 dbuf staging,
//     acc[2] x 2 passes) -- 46.5us / WRITE 4MB.
//   - wsum: 512 x 512thr, fused out + T14 v-prefetch + Madj folded into the
//     MFMA accumulator init (Ms = -(M + log2 den); r-loop = bare exp2+add).
//
// R16 precision scheme (kept): SINGLE fp16 q x fp16 k MFMA per k-slice.
// absmax stayed exactly 0.25 from sigma 0.004 through 0.035 schemes.
//
// K layout (R14, kept): khi = 16KB tiles [bh][tile][128 rows][64 cols],
// intra-row swizzle: granule j at j ^ (row&7). global_load_lds stages
// LINEARLY; ds_read applies the same XOR (swizzle both sides or neither).
typedef __attribute__((ext_vector_type(8)))  _Float16 halfx8;
typedef __attribute__((ext_vector_type(4)))  _Float16 halfx4;
typedef __attribute__((ext_vector_type(16))) float    floatx16;

__device__ inline float fexp2(float x) { return __builtin_amdgcn_exp2f(x); }
__device__ inline float flog2(float x) { return __builtin_amdgcn_logf(x); }

// C/D row for accumulator register r (0..15) given half = lane>>5 (verified R2).
__device__ inline int rowmap(int r, int half) {
    return (r & 3) + 8 * (r >> 2) + 4 * half;
}

// ---------------------------------------------------------------------------
// Pre-convert: q -> fp16 (QSCALE folded), k -> fp16, k swizzled.
// ---------------------------------------------------------------------------
__global__ __launch_bounds__(256) void convert_kernel(const float4* __restrict__ q,
                                                      const float4* __restrict__ k,
                                                      _Float16* __restrict__ qhi,
                                                      _Float16* __restrict__ khi) {
    size_t gid = (size_t)blockIdx.x * 256 + threadIdx.x;  // float4 index, QK/4 total
    float4 qa = q[gid];
    float4 ka = k[gid];
    float qf[4] = {qa.x, qa.y, qa.z, qa.w};
    float kf[4] = {ka.x, ka.y, ka.z, ka.w};
    halfx4 h, kh;
#pragma unroll
    for (int i = 0; i < 4; ++i) {
        h[i]  = (_Float16)(qf[i] * QSCALE);  // RN
        kh[i] = (_Float16)kf[i];
    }
    *(halfx4*)&qhi[gid * 4] = h;
    // swizzled K: row = (gid>>4)&127; granule j = (gid>>1)&7; sub = (gid&1)*4
    size_t rowbase = (gid * 4) & ~(size_t)63;
    int j = (int)((gid >> 1) & 7) ^ (int)((gid >> 4) & 7);
    *(halfx4*)&khi[rowbase + (size_t)(j << 3) + ((gid & 1) << 2)] = kh;
}

// ---------------------------------------------------------------------------
// Async stage: one 16KB K-tile image -> LDS, linear copy, no VGPR round-trip.
// LDS dest = wave-uniform base + lane*16 (HW rule); global src per-lane.
// Tracked by vmcnt; __syncthreads() drains it.  4-wave and 8-wave variants.
// ---------------------------------------------------------------------------
__device__ inline void stage_tile_async4(const _Float16* __restrict__ gtile,
                                         _Float16* lds, int wave, int lane) {
#pragma unroll
    for (int i = 0; i < 4; ++i) {
        const char* gp = (const char*)gtile + wave * 4096 + i * 1024 + lane * 16;
        char* lp = (char*)lds + wave * 4096 + i * 1024;   // wave-uniform
        __builtin_amdgcn_global_load_lds(
            (const __attribute__((address_space(1))) unsigned int*)gp,
            (__attribute__((address_space(3))) unsigned int*)lp, 16, 0, 0);
    }
}
__device__ inline void stage_tile_async8(const _Float16* __restrict__ gtile,
                                         _Float16* lds, int wave, int lane) {
#pragma unroll
    for (int i = 0; i < 2; ++i) {
        const char* gp = (const char*)gtile + wave * 2048 + i * 1024 + lane * 16;
        char* lp = (char*)lds + wave * 2048 + i * 1024;   // wave-uniform
        __builtin_amdgcn_global_load_lds(
            (const __attribute__((address_space(1))) unsigned int*)gp,
            (__attribute__((address_space(3))) unsigned int*)lp, 16, 0, 0);
    }
}

// ---- A-operand fragments: lane holds A[m=lane&31][k=(lane>>5)*8+j] ----------
__device__ inline void load_a(const _Float16* __restrict__ qhi_row,
                              int half, halfx8 ah[4]) {
#pragma unroll
    for (int ks = 0; ks < 4; ++ks)
        ah[ks] = *(const halfx8*)&qhi_row[ks * 16 + half * 8];
}

// ---------------------------------------------------------------------------
// Phase 1: per-row softmax stats (base-2), PARTIAL over an m-half.
// EXACT R6/R20 shape (measured 46.5us): 1D grid 1024: idx = (bh + 32*ms) +
// 64*nblk -> blocks sharing a K-half are congruent mod 8 => same XCD.
// acc[2] x 2 passes (unroll 1) under __launch_bounds__(256,4).
// T5: setprio(1) around each pass's MFMA cluster.
// ---------------------------------------------------------------------------
__global__ __launch_bounds__(256, 4) void stats_kernel(const _Float16* __restrict__ qhi,
                                                       const _Float16* __restrict__ khi,
                                                       float* __restrict__ smax_p,
                                                       float* __restrict__ sden_p) {
    __shared__ _Float16 K2[2 * 128 * 64];  // 32 KB, two tile buffers
    const int g    = blockIdx.x & 63;      // bh + 32*ms
    const int bh   = g & 31;
    const int ms   = g >> 5;               // m-split: tiles [ms*8, ms*8+8)
    const int n0   = (blockIdx.x >> 6) * 128;
    const int tid  = threadIdx.x;
    const int wave = tid >> 6, lane = tid & 63;
    const int half = lane >> 5, l31 = lane & 31;
    const int xr   = l31 & 7;              // row&7 for swizzled reads
    const size_t base = (size_t)bh * NN * DD;

    const _Float16* khi_b = khi + base;
    stage_tile_async4(khi_b + (size_t)(ms * 8) * 8192, K2, wave, lane);

    // A fragments: fixed rows for the whole kernel.
    halfx8 ah[4];
    {
        size_t ro = base + (size_t)(n0 + wave * 32 + l31) * DD;
        load_a(qhi + ro, half, ah);
    }

    float m_run[16], d_run[16];
#pragma unroll
    for (int r = 0; r < 16; ++r) { m_run[r] = -INFINITY; d_run[r] = 0.f; }

    __syncthreads();                       // tile 0 landed (vmcnt drain) + barrier

#pragma unroll 1
    for (int mti = 0; mti < 8; ++mti) {
        const _Float16* Kc = K2 + (mti & 1) * 8192;
        if (mti < 7)                       // issue next tile BEFORE compute
            stage_tile_async4(khi_b + (size_t)(ms * 8 + mti + 1) * 8192,
                              K2 + ((mti + 1) & 1) * 8192, wave, lane);

#pragma unroll 1
        for (int p = 0; p < 2; ++p) {      // two half-width passes: t = 2p+tt
            floatx16 acc[2];
#pragma unroll
            for (int t = 0; t < 2; ++t)
#pragma unroll
                for (int e = 0; e < 16; ++e) acc[t][e] = 0.f;

            __builtin_amdgcn_s_setprio(1);   // T5: favor MFMA-issuing wave
#pragma unroll
            for (int tt = 0; tt < 2; ++tt) {
                const int mr = (p * 2 + tt) * 32 + l31;
                const _Float16* rowp = Kc + (size_t)mr * 64;
#pragma unroll
                for (int ks = 0; ks < 4; ++ks) {
                    const int j = (ks * 2 + half) ^ xr;
                    halfx8 bhf = *(const halfx8*)&rowp[j << 3];
                    acc[tt] = __builtin_amdgcn_mfma_f32_32x32x16_f16(ah[ks], bhf, acc[tt], 0, 0, 0);
                }
            }
            __builtin_amdgcn_s_setprio(0);

            // Lazy per-lane online stats, base-2 domain.
#pragma unroll
            for (int r = 0; r < 16; ++r) {
                float tmax = fmaxf(acc[0][r], acc[1][r]);
                float m_new = fmaxf(m_run[r], tmax);
                float s = fexp2(acc[0][r] - m_new) + fexp2(acc[1][r] - m_new);
                d_run[r] = d_run[r] * fexp2(m_run[r] - m_new) + s;
                m_run[r] = m_new;
            }
        }

        if (mti < 7) __syncthreads();      // t+1 loads landed + all waves done with Kc
    }

    // Cross-lane combine within each 32-lane half (rows differ across halves).
    float* smp = smax_p + ((size_t)ms * BH + bh) * NN;
    float* sdp = sden_p + ((size_t)ms * BH + bh) * NN;
#pragma unroll
    for (int r = 0; r < 16; ++r) {
        float M = m_run[r];
#pragma unroll
        for (int off = 1; off < 32; off <<= 1)
            M = fmaxf(M, __shfl_xor(M, off));
        float dd = d_run[r] * fexp2(m_run[r] - M);
#pragma unroll
        for (int off = 1; off < 32; off <<= 1)
            dd += __shfl_xor(dd, off);
        if (l31 == 0) {
            int row = n0 + wave * 32 + rowmap(r, half);
            smp[row] = M;
            sdp[row] = dd;
        }
    }
}

// ---------------------------------------------------------------------------
// Phase 2 (R20): w[m] over ALL rows + fused output.  Grid 512 = bh + 32*m0i,
// 512 threads (8 waves).  Block owns 128 cols; K tile staged once; waves
// stride 64 row-strips of 32.  Ms holds NEGATED Madj = -(M + log2 den);
// the MFMA accumulator is INITIALIZED with it, so the C-input performs the
// subtraction exactly and the r-loop is a bare exp2 + add.
// T14 v-prefetch; T5 setprio around the MFMA cluster.
// ---------------------------------------------------------------------------
__global__ __launch_bounds__(512, 4) void wsum_kernel(const _Float16* __restrict__ qhi,
                                                      const _Float16* __restrict__ khi,
                                                      const float* __restrict__ smax_p,
                                                      const float* __restrict__ sden_p,
                                                      const float* __restrict__ v,
                                                      float* __restrict__ out) {
    __shared__ _Float16 Khi[128 * 64];     // 16 KB, single tile
    __shared__ float Ms[2048];             // 8 KB: -(M + log2 den) for all rows
    __shared__ float wred[8 * 128];        // 4 KB
    __shared__ float wfin[128];
    const int b    = blockIdx.x;
    const int bh   = b & 31;
    const int m0   = (b >> 5) * 128;       // col block
    const int tid  = threadIdx.x;
    const int wave = tid >> 6, lane = tid & 63;
    const int half = lane >> 5, l31 = lane & 31;
    const int xr   = l31 & 7;
    const size_t base = (size_t)bh * NN * DD;

    stage_tile_async8(khi + base + (size_t)m0 * 64, Khi, wave, lane);

    {   // combine row stats inline (4 rows/thread) while the tile streams in
        size_t roff = (size_t)bh * NN + tid * 4;
        float4 m0v = *(const float4*)&smax_p[roff];
        float4 m1v = *(const float4*)&smax_p[(size_t)BHNN + roff];
        float4 d0v = *(const float4*)&sden_p[roff];
        float4 d1v = *(const float4*)&sden_p[(size_t)BHNN + roff];
        float mm0[4] = {m0v.x, m0v.y, m0v.z, m0v.w};
        float mm1[4] = {m1v.x, m1v.y, m1v.z, m1v.w};
        float dd0[4] = {d0v.x, d0v.y, d0v.z, d0v.w};
        float dd1[4] = {d1v.x, d1v.y, d1v.z, d1v.w};
#pragma unroll
        for (int j = 0; j < 4; ++j) {
            float M = fmaxf(mm0[j], mm1[j]);
            float den = dd0[j] * fexp2(mm0[j] - M) + dd1[j] * fexp2(mm1[j] - M);
            Ms[tid * 4 + j] = -(M + flog2(den));   // negated Madj
        }
    }
    __syncthreads();                       // K tile landed + Ms visible

    float wacc0 = 0.f, wacc1 = 0.f, wacc2 = 0.f, wacc3 = 0.f;

#pragma unroll 1
    for (int it = 0; it < 8; ++it) {
        const int ls = wave + it * 8;      // local strip 0..63 (32 rows each)
        halfx8 ah[4];
        {
            size_t ro = base + (size_t)(ls * 32 + l31) * DD;
            load_a(qhi + ro, half, ah);
        }

#pragma unroll 1
        for (int p = 0; p < 2; ++p) {
            floatx16 acc[2];
#pragma unroll
            for (int e = 0; e < 16; ++e) {
                float mb = Ms[ls * 32 + rowmap(e, half)];  // broadcast LDS read
                acc[0][e] = mb;
                acc[1][e] = mb;
            }

            __builtin_amdgcn_s_setprio(1);   // T5: favor MFMA-issuing wave
#pragma unroll
            for (int tt = 0; tt < 2; ++tt) {
                const int mr = (p * 2 + tt) * 32 + l31;
                const _Float16* rowp = Khi + (size_t)mr * 64;
#pragma unroll
                for (int ks = 0; ks < 4; ++ks) {
                    const int j = (ks * 2 + half) ^ xr;
                    halfx8 bhf = *(const halfx8*)&rowp[j << 3];
                    acc[tt] = __builtin_amdgcn_mfma_f32_32x32x16_f16(ah[ks], bhf, acc[tt], 0, 0, 0);
                }
            }
            __builtin_amdgcn_s_setprio(0);

            float w0 = 0.f, w1 = 0.f;
#pragma unroll
            for (int r = 0; r < 16; ++r) {
                w0 += fexp2(acc[0][r]);
                w1 += fexp2(acc[1][r]);
            }
            if (p == 0) { wacc0 += w0; wacc1 += w1; }
            else        { wacc2 += w0; wacc3 += w1; }
        }
    }

    // T14 v-prefetch: issue the epilogue's v reads now; they land under the
    // reduction barriers below.
    const float4* v4 = (const float4*)(v + base + (size_t)m0 * DD);
    float4 vpre[4];
#pragma unroll
    for (int i = 0; i < 4; ++i) vpre[i] = v4[tid + 512 * i];

    // halves hold same cols, different rows: fold halves, then the 8 waves.
    float wacc[4] = {wacc0, wacc1, wacc2, wacc3};
#pragma unroll
    for (int t = 0; t < 4; ++t) wacc[t] += __shfl_xor(wacc[t], 32);
    if (half == 0) {
#pragma unroll
        for (int t = 0; t < 4; ++t) wred[wave * 128 + t * 32 + l31] = wacc[t];
    }
    __syncthreads();
    if (tid < 128) {
        float s = 0.f;
#pragma unroll
        for (int w = 0; w < 8; ++w) s += wred[w * 128 + tid];
        wfin[tid] = s;
    }
    __syncthreads();

    // Fused epilogue: out[m, :] = wfin[m - m0] * v[m, :] for m in [m0, m0+128).
    float4* o4 = (float4*)(out + base + (size_t)m0 * DD);
#pragma unroll
    for (int i = 0; i < 4; ++i) {
        int idx = tid + 512 * i;           // 2048 float4s = 128 rows x 16
        float ww = wfin[idx >> 4];
        o4[idx] = make_float4(vpre[i].x * ww, vpre[i].y * ww,
                              vpre[i].z * ww, vpre[i].w * ww);
    }
}

extern "C" void kernel_launch(void* const* d_in, const int* in_sizes, int n_in,
                              void* d_out, int out_size, void* d_ws, size_t ws_size,
                              hipStream_t stream) {
    const float* q = (const float*)d_in[0];
    const float* k = (const float*)d_in[1];
    const float* v = (const float*)d_in[2];
    float* out = (float*)d_out;

    // Workspace (~17 MB), all fully rewritten each launch:
    _Float16* qhi = (_Float16*)d_ws;
    _Float16* khi = qhi + QK;
    float* smax_p = (float*)(khi + QK);       // 2*BHNN
    float* sden_p = smax_p + 2 * BHNN;        // 2*BHNN

    convert_kernel<<<QK / 4 / 256, 256, 0, stream>>>((const float4*)q, (const float4*)k,
                                                     qhi, khi);
    stats_kernel<<<1024, 256, 0, stream>>>(qhi, khi, smax_p, sden_p);
    wsum_kernel<<<512, 512, 0, stream>>>(qhi, khi, smax_p, sden_p, v, out);
}

// Round 14
// 154.214 us; speedup vs baseline: 1.9670x; 1.0132x over previous
//
#include <hip/hip_runtime.h>
#include <math.h>

// q,k,v: [B=2, H=16, N=2048, Dh=64] fp32.  BH = 32 independent heads.
#define BH 32
#define NN 2048
#define DD 64
#define BHNN (BH * NN)        // 65536 rows total
#define QK ((size_t)BH * NN * DD)  // 4,194,304 elems per tensor

// 8 * log2(e): logits produced in base-2 domain so all softmax exps are a bare
// v_exp_f32 (exp2). Softmax is invariant to the base change.
#define QSCALE 11.5415603f

// R24 = R20 verbatim (measured best: 155.5us). Final consolidation.
//   R23 measured T5 setprio at slightly NEGATIVE (stats 46.5 -> 48.4us,
//   total +0.8us) -> removed. Ceiling evidence, all measured:
//   - Spill wall (R12/R13/R15/R19/R21): >48 live accumulator-class regs
//     under the 128 cap scratches; 4 waves/SIMD is this algorithm's max.
//   - MFMA already minimal: single fp16 x fp16 per k-slice; MfmaUtil 14% =
//     6.3us of stats' 46.5us. Softmax exp2/VALU (~52% busy) is the
//     algorithm's required work and the dominant pipe.
//   - Fusion +1.2us (R17); cooperative launch fails harness (R18); ~50us of
//     dur_us is launch-count-insensitive harness overhead.
//   - T15 pipeline catastrophic spill (R21); stats-pairing -4us (R19).
//
// R20 content (all measured):
//   - stats: R6 shape (grid 1024 x 256thr, (256,4), async4 dbuf staging,
//     acc[2] x 2 passes) -- 46.5us / WRITE 4MB.
//   - wsum: 512 x 512thr, fused out + T14 v-prefetch + Madj folded into the
//     MFMA accumulator init (Ms = -(M + log2 den); r-loop = bare exp2+add).
//
// R16 precision scheme: SINGLE fp16 q x fp16 k MFMA per k-slice.
// absmax stayed exactly 0.25 from sigma 0.004 through 0.035 schemes.
//
// K layout (R14): khi = 16KB tiles [bh][tile][128 rows][64 cols],
// intra-row swizzle: granule j at j ^ (row&7). global_load_lds stages
// LINEARLY; ds_read applies the same XOR (swizzle both sides or neither).
typedef __attribute__((ext_vector_type(8)))  _Float16 halfx8;
typedef __attribute__((ext_vector_type(4)))  _Float16 halfx4;
typedef __attribute__((ext_vector_type(16))) float    floatx16;

__device__ inline float fexp2(float x) { return __builtin_amdgcn_exp2f(x); }
__device__ inline float flog2(float x) { return __builtin_amdgcn_logf(x); }

// C/D row for accumulator register r (0..15) given half = lane>>5 (verified R2).
__device__ inline int rowmap(int r, int half) {
    return (r & 3) + 8 * (r >> 2) + 4 * half;
}

// ---------------------------------------------------------------------------
// Pre-convert: q -> fp16 (QSCALE folded), k -> fp16, k swizzled.
// ---------------------------------------------------------------------------
__global__ __launch_bounds__(256) void convert_kernel(const float4* __restrict__ q,
                                                      const float4* __restrict__ k,
                                                      _Float16* __restrict__ qhi,
                                                      _Float16* __restrict__ khi) {
    size_t gid = (size_t)blockIdx.x * 256 + threadIdx.x;  // float4 index, QK/4 total
    float4 qa = q[gid];
    float4 ka = k[gid];
    float qf[4] = {qa.x, qa.y, qa.z, qa.w};
    float kf[4] = {ka.x, ka.y, ka.z, ka.w};
    halfx4 h, kh;
#pragma unroll
    for (int i = 0; i < 4; ++i) {
        h[i]  = (_Float16)(qf[i] * QSCALE);  // RN
        kh[i] = (_Float16)kf[i];
    }
    *(halfx4*)&qhi[gid * 4] = h;
    // swizzled K: row = (gid>>4)&127; granule j = (gid>>1)&7; sub = (gid&1)*4
    size_t rowbase = (gid * 4) & ~(size_t)63;
    int j = (int)((gid >> 1) & 7) ^ (int)((gid >> 4) & 7);
    *(halfx4*)&khi[rowbase + (size_t)(j << 3) + ((gid & 1) << 2)] = kh;
}

// ---------------------------------------------------------------------------
// Async stage: one 16KB K-tile image -> LDS, linear copy, no VGPR round-trip.
// LDS dest = wave-uniform base + lane*16 (HW rule); global src per-lane.
// Tracked by vmcnt; __syncthreads() drains it.  4-wave and 8-wave variants.
// ---------------------------------------------------------------------------
__device__ inline void stage_tile_async4(const _Float16* __restrict__ gtile,
                                         _Float16* lds, int wave, int lane) {
#pragma unroll
    for (int i = 0; i < 4; ++i) {
        const char* gp = (const char*)gtile + wave * 4096 + i * 1024 + lane * 16;
        char* lp = (char*)lds + wave * 4096 + i * 1024;   // wave-uniform
        __builtin_amdgcn_global_load_lds(
            (const __attribute__((address_space(1))) unsigned int*)gp,
            (__attribute__((address_space(3))) unsigned int*)lp, 16, 0, 0);
    }
}
__device__ inline void stage_tile_async8(const _Float16* __restrict__ gtile,
                                         _Float16* lds, int wave, int lane) {
#pragma unroll
    for (int i = 0; i < 2; ++i) {
        const char* gp = (const char*)gtile + wave * 2048 + i * 1024 + lane * 16;
        char* lp = (char*)lds + wave * 2048 + i * 1024;   // wave-uniform
        __builtin_amdgcn_global_load_lds(
            (const __attribute__((address_space(1))) unsigned int*)gp,
            (__attribute__((address_space(3))) unsigned int*)lp, 16, 0, 0);
    }
}

// ---- A-operand fragments: lane holds A[m=lane&31][k=(lane>>5)*8+j] ----------
__device__ inline void load_a(const _Float16* __restrict__ qhi_row,
                              int half, halfx8 ah[4]) {
#pragma unroll
    for (int ks = 0; ks < 4; ++ks)
        ah[ks] = *(const halfx8*)&qhi_row[ks * 16 + half * 8];
}

// ---------------------------------------------------------------------------
// Phase 1: per-row softmax stats (base-2), PARTIAL over an m-half.
// EXACT R6/R20 shape (measured 46.5us): 1D grid 1024: idx = (bh + 32*ms) +
// 64*nblk -> blocks sharing a K-half are congruent mod 8 => same XCD.
// acc[2] x 2 passes (unroll 1) under __launch_bounds__(256,4).
// ---------------------------------------------------------------------------
__global__ __launch_bounds__(256, 4) void stats_kernel(const _Float16* __restrict__ qhi,
                                                       const _Float16* __restrict__ khi,
                                                       float* __restrict__ smax_p,
                                                       float* __restrict__ sden_p) {
    __shared__ _Float16 K2[2 * 128 * 64];  // 32 KB, two tile buffers
    const int g    = blockIdx.x & 63;      // bh + 32*ms
    const int bh   = g & 31;
    const int ms   = g >> 5;               // m-split: tiles [ms*8, ms*8+8)
    const int n0   = (blockIdx.x >> 6) * 128;
    const int tid  = threadIdx.x;
    const int wave = tid >> 6, lane = tid & 63;
    const int half = lane >> 5, l31 = lane & 31;
    const int xr   = l31 & 7;              // row&7 for swizzled reads
    const size_t base = (size_t)bh * NN * DD;

    const _Float16* khi_b = khi + base;
    stage_tile_async4(khi_b + (size_t)(ms * 8) * 8192, K2, wave, lane);

    // A fragments: fixed rows for the whole kernel.
    halfx8 ah[4];
    {
        size_t ro = base + (size_t)(n0 + wave * 32 + l31) * DD;
        load_a(qhi + ro, half, ah);
    }

    float m_run[16], d_run[16];
#pragma unroll
    for (int r = 0; r < 16; ++r) { m_run[r] = -INFINITY; d_run[r] = 0.f; }

    __syncthreads();                       // tile 0 landed (vmcnt drain) + barrier

#pragma unroll 1
    for (int mti = 0; mti < 8; ++mti) {
        const _Float16* Kc = K2 + (mti & 1) * 8192;
        if (mti < 7)                       // issue next tile BEFORE compute
            stage_tile_async4(khi_b + (size_t)(ms * 8 + mti + 1) * 8192,
                              K2 + ((mti + 1) & 1) * 8192, wave, lane);

#pragma unroll 1
        for (int p = 0; p < 2; ++p) {      // two half-width passes: t = 2p+tt
            floatx16 acc[2];
#pragma unroll
            for (int t = 0; t < 2; ++t)
#pragma unroll
                for (int e = 0; e < 16; ++e) acc[t][e] = 0.f;

#pragma unroll
            for (int tt = 0; tt < 2; ++tt) {
                const int mr = (p * 2 + tt) * 32 + l31;
                const _Float16* rowp = Kc + (size_t)mr * 64;
#pragma unroll
                for (int ks = 0; ks < 4; ++ks) {
                    const int j = (ks * 2 + half) ^ xr;
                    halfx8 bhf = *(const halfx8*)&rowp[j << 3];
                    acc[tt] = __builtin_amdgcn_mfma_f32_32x32x16_f16(ah[ks], bhf, acc[tt], 0, 0, 0);
                }
            }

            // Lazy per-lane online stats, base-2 domain.
#pragma unroll
            for (int r = 0; r < 16; ++r) {
                float tmax = fmaxf(acc[0][r], acc[1][r]);
                float m_new = fmaxf(m_run[r], tmax);
                float s = fexp2(acc[0][r] - m_new) + fexp2(acc[1][r] - m_new);
                d_run[r] = d_run[r] * fexp2(m_run[r] - m_new) + s;
                m_run[r] = m_new;
            }
        }

        if (mti < 7) __syncthreads();      // t+1 loads landed + all waves done with Kc
    }

    // Cross-lane combine within each 32-lane half (rows differ across halves).
    float* smp = smax_p + ((size_t)ms * BH + bh) * NN;
    float* sdp = sden_p + ((size_t)ms * BH + bh) * NN;
#pragma unroll
    for (int r = 0; r < 16; ++r) {
        float M = m_run[r];
#pragma unroll
        for (int off = 1; off < 32; off <<= 1)
            M = fmaxf(M, __shfl_xor(M, off));
        float dd = d_run[r] * fexp2(m_run[r] - M);
#pragma unroll
        for (int off = 1; off < 32; off <<= 1)
            dd += __shfl_xor(dd, off);
        if (l31 == 0) {
            int row = n0 + wave * 32 + rowmap(r, half);
            smp[row] = M;
            sdp[row] = dd;
        }
    }
}

// ---------------------------------------------------------------------------
// Phase 2 (R20): w[m] over ALL rows + fused output.  Grid 512 = bh + 32*m0i,
// 512 threads (8 waves).  Block owns 128 cols; K tile staged once; waves
// stride 64 row-strips of 32.  Ms holds NEGATED Madj = -(M + log2 den);
// the MFMA accumulator is INITIALIZED with it, so the C-input performs the
// subtraction exactly and the r-loop is a bare exp2 + add.
// T14 v-prefetch: epilogue's v reads issued before the reduction barriers.
// ---------------------------------------------------------------------------
__global__ __launch_bounds__(512, 4) void wsum_kernel(const _Float16* __restrict__ qhi,
                                                      const _Float16* __restrict__ khi,
                                                      const float* __restrict__ smax_p,
                                                      const float* __restrict__ sden_p,
                                                      const float* __restrict__ v,
                                                      float* __restrict__ out) {
    __shared__ _Float16 Khi[128 * 64];     // 16 KB, single tile
    __shared__ float Ms[2048];             // 8 KB: -(M + log2 den) for all rows
    __shared__ float wred[8 * 128];        // 4 KB
    __shared__ float wfin[128];
    const int b    = blockIdx.x;
    const int bh   = b & 31;
    const int m0   = (b >> 5) * 128;       // col block
    const int tid  = threadIdx.x;
    const int wave = tid >> 6, lane = tid & 63;
    const int half = lane >> 5, l31 = lane & 31;
    const int xr   = l31 & 7;
    const size_t base = (size_t)bh * NN * DD;

    stage_tile_async8(khi + base + (size_t)m0 * 64, Khi, wave, lane);

    {   // combine row stats inline (4 rows/thread) while the tile streams in
        size_t roff = (size_t)bh * NN + tid * 4;
        float4 m0v = *(const float4*)&smax_p[roff];
        float4 m1v = *(const float4*)&smax_p[(size_t)BHNN + roff];
        float4 d0v = *(const float4*)&sden_p[roff];
        float4 d1v = *(const float4*)&sden_p[(size_t)BHNN + roff];
        float mm0[4] = {m0v.x, m0v.y, m0v.z, m0v.w};
        float mm1[4] = {m1v.x, m1v.y, m1v.z, m1v.w};
        float dd0[4] = {d0v.x, d0v.y, d0v.z, d0v.w};
        float dd1[4] = {d1v.x, d1v.y, d1v.z, d1v.w};
#pragma unroll
        for (int j = 0; j < 4; ++j) {
            float M = fmaxf(mm0[j], mm1[j]);
            float den = dd0[j] * fexp2(mm0[j] - M) + dd1[j] * fexp2(mm1[j] - M);
            Ms[tid * 4 + j] = -(M + flog2(den));   // negated Madj
        }
    }
    __syncthreads();                       // K tile landed + Ms visible

    float wacc0 = 0.f, wacc1 = 0.f, wacc2 = 0.f, wacc3 = 0.f;

#pragma unroll 1
    for (int it = 0; it < 8; ++it) {
        const int ls = wave + it * 8;      // local strip 0..63 (32 rows each)
        halfx8 ah[4];
        {
            size_t ro = base + (size_t)(ls * 32 + l31) * DD;
            load_a(qhi + ro, half, ah);
        }

#pragma unroll 1
        for (int p = 0; p < 2; ++p) {
            floatx16 acc[2];
#pragma unroll
            for (int e = 0; e < 16; ++e) {
                float mb = Ms[ls * 32 + rowmap(e, half)];  // broadcast LDS read
                acc[0][e] = mb;
                acc[1][e] = mb;
            }

#pragma unroll
            for (int tt = 0; tt < 2; ++tt) {
                const int mr = (p * 2 + tt) * 32 + l31;
                const _Float16* rowp = Khi + (size_t)mr * 64;
#pragma unroll
                for (int ks = 0; ks < 4; ++ks) {
                    const int j = (ks * 2 + half) ^ xr;
                    halfx8 bhf = *(const halfx8*)&rowp[j << 3];
                    acc[tt] = __builtin_amdgcn_mfma_f32_32x32x16_f16(ah[ks], bhf, acc[tt], 0, 0, 0);
                }
            }

            float w0 = 0.f, w1 = 0.f;
#pragma unroll
            for (int r = 0; r < 16; ++r) {
                w0 += fexp2(acc[0][r]);
                w1 += fexp2(acc[1][r]);
            }
            if (p == 0) { wacc0 += w0; wacc1 += w1; }
            else        { wacc2 += w0; wacc3 += w1; }
        }
    }

    // T14 v-prefetch: issue the epilogue's v reads now; they land under the
    // reduction barriers below.
    const float4* v4 = (const float4*)(v + base + (size_t)m0 * DD);
    float4 vpre[4];
#pragma unroll
    for (int i = 0; i < 4; ++i) vpre[i] = v4[tid + 512 * i];

    // halves hold same cols, different rows: fold halves, then the 8 waves.
    float wacc[4] = {wacc0, wacc1, wacc2, wacc3};
#pragma unroll
    for (int t = 0; t < 4; ++t) wacc[t] += __shfl_xor(wacc[t], 32);
    if (half == 0) {
#pragma unroll
        for (int t = 0; t < 4; ++t) wred[wave * 128 + t * 32 + l31] = wacc[t];
    }
    __syncthreads();
    if (tid < 128) {
        float s = 0.f;
#pragma unroll
        for (int w = 0; w < 8; ++w) s += wred[w * 128 + tid];
        wfin[tid] = s;
    }
    __syncthreads();

    // Fused epilogue: out[m, :] = wfin[m - m0] * v[m, :] for m in [m0, m0+128).
    float4* o4 = (float4*)(out + base + (size_t)m0 * DD);
#pragma unroll
    for (int i = 0; i < 4; ++i) {
        int idx = tid + 512 * i;           // 2048 float4s = 128 rows x 16
        float ww = wfin[idx >> 4];
        o4[idx] = make_float4(vpre[i].x * ww, vpre[i].y * ww,
                              vpre[i].z * ww, vpre[i].w * ww);
    }
}

extern "C" void kernel_launch(void* const* d_in, const int* in_sizes, int n_in,
                              void* d_out, int out_size, void* d_ws, size_t ws_size,
                              hipStream_t stream) {
    const float* q = (const float*)d_in[0];
    const float* k = (const float*)d_in[1];
    const float* v = (const float*)d_in[2];
    float* out = (float*)d_out;

    // Workspace (~17 MB), all fully rewritten each launch:
    _Float16* qhi = (_Float16*)d_ws;
    _Float16* khi = qhi + QK;
    float* smax_p = (float*)(khi + QK);       // 2*BHNN
    float* sden_p = smax_p + 2 * BHNN;        // 2*BHNN

    convert_kernel<<<QK / 4 / 256, 256, 0, stream>>>((const float4*)q, (const float4*)k,
                                                     qhi, khi);
    stats_kernel<<<1024, 256, 0, stream>>>(qhi, khi, smax_p, sden_p);
    wsum_kernel<<<512, 512, 0, stream>>>(qhi, khi, smax_p, sden_p, v, out);
}